// Round 3
// baseline (171.516 us; speedup 1.0000x reference)
//
#include <hip/hip_runtime.h>

// Problem constants: N=20000, T=4, F_IN=F_OUT=64, E=640000
#define N_NODES 20000
#define T_STEPS 4
#define F_DIM   64
#define E_EDGES 640000
#define ROWS    (N_NODES * T_STEPS)   // 80000
#define ROW_ELEMS (T_STEPS * F_DIM)   // 256 elems per node row

#define SCATTER_BLOCKS   (E_EDGES / 1024)     // 625 (256 thr x 4 edges)
#define TRANSFORM_BLOCKS (ROWS / 64)          // 1250
#define OVF_CAP          4096

__device__ __forceinline__ unsigned short f32_to_bf16_rne(float f) {
    unsigned u = __float_as_uint(f);
    u += 0x7FFFu + ((u >> 16) & 1u);
    return (unsigned short)(u >> 16);
}
__device__ __forceinline__ float bf16_to_f32(unsigned short h) {
    return __uint_as_float((unsigned)h << 16);
}
// 12-bit fixed-point weight in [0,1): abs err <= 2^-13 (better than bf16's
// 2e-3 near 1.0). Four weights + 16-bit src pack into ONE 8-byte record.
__device__ __forceinline__ unsigned w_to_u12(float f) {
    unsigned q = __float2uint_rn(f * 4096.0f);
    return q > 4095u ? 4095u : q;
}

// ---------------------------------------------------------------------------
// Fused kernel.
//  R2 post-mortem: WRITE_SIZE identical for 8B and 16B records (49.8 MB) —
//  amplification is per-store line-allocate (640k x 64B = 41MB), payload-
//  independent. Kernel is NOT BW-bound (16% peak): it is LATENCY-bound at
//  32% occupancy, capped by the 34.8KB static LDS that even scatter blocks
//  reserve (4 blocks/CU). R3 change: LDS -> 16.4KB (W^T only, stride 64,
//  conflict-free); x streams from global as float4 (rg-group lanes share
//  addresses -> coalesced broadcast). Cap rises to 8-9 blocks/CU so the
//  scatter's ~800cy atomic->store chains hide under 2x the waves.
//  blocks [0, 625):      bucket scatter — 4 edges/thread, 8B uint2 record:
//                        src(16b) | w0..w3(12b fixed-point).
//  blocks [625, 1875):   transform — y = x @ W^T (64x64 fp32) stored bf16.
// ---------------------------------------------------------------------------
__global__ __launch_bounds__(256) void fused_build_kernel(
    const float* __restrict__ x, const float* __restrict__ W,
    unsigned short* __restrict__ yb,
    const int* __restrict__ src, const int* __restrict__ dst,
    const float* __restrict__ ew,
    int* __restrict__ cnt, uint2* __restrict__ buckets, int cap,
    int4* __restrict__ ovf, int* __restrict__ ovf_cnt)
{
    __shared__ float wt[64 * 64];   // W^T, stride 64: 16 KB total

    if (blockIdx.x < SCATTER_BLOCKS) {
        const int base = blockIdx.x * 1024 + threadIdx.x;
#pragma unroll
        for (int j = 0; j < 4; ++j) {
            const int e = base + j * 256;
            const unsigned w0 = w_to_u12(ew[e]);
            const unsigned w1 = w_to_u12(ew[E_EDGES + e]);
            const unsigned w2 = w_to_u12(ew[2 * E_EDGES + e]);
            const unsigned w3 = w_to_u12(ew[3 * E_EDGES + e]);
            const unsigned s  = (unsigned)src[e];
            const unsigned lo = s | (w0 << 16) | (w1 << 28);       // w1 bits 0..3
            const unsigned hi = (w1 >> 4) | (w2 << 8) | (w3 << 20);
            const int d = dst[e];
            const int pos = atomicAdd(&cnt[d], 1);
            if (pos < cap) {
                buckets[(size_t)d * cap + pos] = make_uint2(lo, hi);
            } else {
                const int o = atomicAdd(ovf_cnt, 1);
                if (o < OVF_CAP) { int4 r; r.x = (int)lo; r.y = (int)hi; r.z = d; r.w = 0; ovf[o] = r; }
            }
        }
        return;
    }

    // ---- transform part: y = x @ W^T, x streamed from global ----
    const int tid  = threadIdx.x;
    const int row0 = (blockIdx.x - SCATTER_BLOCKS) * 64;

    // W^T into LDS: wt[f*64 + o] = W[o*64 + f].
    // Write banks: lanes o=0..63, same f -> bank=o%32, 2 lanes/bank (free).
    {
        const int o  = tid & 63;
        const int fb = (tid >> 6) * 16;
#pragma unroll
        for (int k = 0; k < 16; ++k) {
            const int f = fb + k;
            wt[f * 64 + o] = W[o * 64 + f];
        }
    }
    __syncthreads();

    const int rg = tid >> 4;          // 0..15: row group (4 rows)
    const int oq = (tid & 15) * 4;    // output quad

    float acc[4][4];
#pragma unroll
    for (int i = 0; i < 4; ++i)
#pragma unroll
        for (int j = 0; j < 4; ++j) acc[i][j] = 0.0f;

    // x rows for this thread, as float4 chunks (16 chunks of 4 floats per row).
    const float4* xg4 = (const float4*)(x + (size_t)(row0 + rg * 4) * 64);

#pragma unroll 4
    for (int fc = 0; fc < 16; ++fc) {
        float4 xv[4];
#pragma unroll
        for (int i = 0; i < 4; ++i) xv[i] = xg4[i * 16 + fc];
#pragma unroll
        for (int j = 0; j < 4; ++j) {
            const int f = fc * 4 + j;
            const float4 w4 = *(const float4*)&wt[f * 64 + oq];
            const float xj0 = j == 0 ? xv[0].x : j == 1 ? xv[0].y : j == 2 ? xv[0].z : xv[0].w;
            const float xj1 = j == 0 ? xv[1].x : j == 1 ? xv[1].y : j == 2 ? xv[1].z : xv[1].w;
            const float xj2 = j == 0 ? xv[2].x : j == 1 ? xv[2].y : j == 2 ? xv[2].z : xv[2].w;
            const float xj3 = j == 0 ? xv[3].x : j == 1 ? xv[3].y : j == 2 ? xv[3].z : xv[3].w;
            acc[0][0] += xj0 * w4.x; acc[0][1] += xj0 * w4.y; acc[0][2] += xj0 * w4.z; acc[0][3] += xj0 * w4.w;
            acc[1][0] += xj1 * w4.x; acc[1][1] += xj1 * w4.y; acc[1][2] += xj1 * w4.z; acc[1][3] += xj1 * w4.w;
            acc[2][0] += xj2 * w4.x; acc[2][1] += xj2 * w4.y; acc[2][2] += xj2 * w4.z; acc[2][3] += xj2 * w4.w;
            acc[3][0] += xj3 * w4.x; acc[3][1] += xj3 * w4.y; acc[3][2] += xj3 * w4.z; acc[3][3] += xj3 * w4.w;
        }
    }

#pragma unroll
    for (int i = 0; i < 4; ++i) {
        const int r = row0 + rg * 4 + i;
        ushort4 h;
        h.x = f32_to_bf16_rne(acc[i][0]);
        h.y = f32_to_bf16_rne(acc[i][1]);
        h.z = f32_to_bf16_rne(acc[i][2]);
        h.w = f32_to_bf16_rne(acc[i][3]);
        *(ushort4*)(yb + (size_t)r * 64 + oq) = h;
    }
}

// Per-lane weight decode: t = lane>>4 selects w_t, shift = 16 + 12*t.
__device__ __forceinline__ float dec_w(uint2 r, int t) {
    const unsigned long long pk = (unsigned long long)r.x |
                                  ((unsigned long long)r.y << 32);
    const unsigned q = (unsigned)(pk >> (16 + 12 * t)) & 0xFFFu;
    return (float)q * (1.0f / 4096.0f);
}

// ---------------------------------------------------------------------------
// Accumulate: one 64-lane wave per node, 4 nodes/block. Lane l owns elems
// [l*4, l*4+4); t = l>>4. Records are self-contained 8B (one contiguous
// broadcast load per edge — no secondary random indirection). 16-deep
// pipelined gathers. Overflow fixup fused (normally empty).
// ---------------------------------------------------------------------------
__global__ __launch_bounds__(256) void accumulate_kernel(
    const unsigned short* __restrict__ yb, const int* __restrict__ cnt,
    const uint2* __restrict__ buckets, int cap,
    const int4* __restrict__ ovf, const int* __restrict__ ovf_cnt,
    const float* __restrict__ b, float* __restrict__ out)
{
    const int lane = threadIdx.x & 63;
    const int n    = blockIdx.x * 4 + (threadIdx.x >> 6);
    const int t    = lane >> 4;
    const int l4   = lane * 4;

    int deg = cnt[n];
    if (deg > cap) deg = cap;
    const uint2* rp = buckets + (size_t)n * cap;

    float4 acc = make_float4(0.f, 0.f, 0.f, 0.f);

    int k = 0;
    for (; k + 16 <= deg; k += 16) {
        uint2 r[16];
#pragma unroll
        for (int i = 0; i < 16; ++i) r[i] = rp[k + i];
        ushort4 v[16];
#pragma unroll
        for (int i = 0; i < 16; ++i)
            v[i] = *(const ushort4*)(yb + (size_t)(r[i].x & 0xFFFFu) * ROW_ELEMS + l4);
#pragma unroll
        for (int i = 0; i < 16; ++i) {
            const float w = dec_w(r[i], t);
            acc.x += bf16_to_f32(v[i].x) * w;
            acc.y += bf16_to_f32(v[i].y) * w;
            acc.z += bf16_to_f32(v[i].z) * w;
            acc.w += bf16_to_f32(v[i].w) * w;
        }
    }
    for (; k + 4 <= deg; k += 4) {
        uint2 r[4];
#pragma unroll
        for (int i = 0; i < 4; ++i) r[i] = rp[k + i];
        ushort4 v[4];
#pragma unroll
        for (int i = 0; i < 4; ++i)
            v[i] = *(const ushort4*)(yb + (size_t)(r[i].x & 0xFFFFu) * ROW_ELEMS + l4);
#pragma unroll
        for (int i = 0; i < 4; ++i) {
            const float w = dec_w(r[i], t);
            acc.x += bf16_to_f32(v[i].x) * w;
            acc.y += bf16_to_f32(v[i].y) * w;
            acc.z += bf16_to_f32(v[i].z) * w;
            acc.w += bf16_to_f32(v[i].w) * w;
        }
    }
    for (; k < deg; ++k) {
        const uint2 r = rp[k];
        const float w = dec_w(r, t);
        const ushort4 v = *(const ushort4*)(yb + (size_t)(r.x & 0xFFFFu) * ROW_ELEMS + l4);
        acc.x += bf16_to_f32(v.x) * w;
        acc.y += bf16_to_f32(v.y) * w;
        acc.z += bf16_to_f32(v.z) * w;
        acc.w += bf16_to_f32(v.w) * w;
    }

    // ---- fused overflow fixup (normally m == 0: one broadcast load) ----
    {
        int m = *ovf_cnt;
        if (m > OVF_CAP) m = OVF_CAP;
        for (int i = 0; i < m; ++i) {
            const int4 rr = ovf[i];
            if (rr.z == n) {
                const uint2 r = make_uint2((unsigned)rr.x, (unsigned)rr.y);
                const float w = dec_w(r, t);
                const ushort4 v = *(const ushort4*)(yb + (size_t)(r.x & 0xFFFFu) * ROW_ELEMS + l4);
                acc.x += bf16_to_f32(v.x) * w;
                acc.y += bf16_to_f32(v.y) * w;
                acc.z += bf16_to_f32(v.z) * w;
                acc.w += bf16_to_f32(v.w) * w;
            }
        }
    }

    const float4 bv = *(const float4*)(b + (lane & 15) * 4);
    acc.x += bv.x; acc.y += bv.y; acc.z += bv.z; acc.w += bv.w;
    *(float4*)(out + (size_t)n * ROW_ELEMS + l4) = acc;
}

extern "C" void kernel_launch(void* const* d_in, const int* in_sizes, int n_in,
                              void* d_out, int out_size, void* d_ws, size_t ws_size,
                              hipStream_t stream) {
    const float* x   = (const float*)d_in[0];  // (N,T,64)
    const float* ew  = (const float*)d_in[1];  // (T,E)
    const int*   src = (const int*)  d_in[2];  // (E,)
    const int*   dst = (const int*)  d_in[3];  // (E,)
    const float* W   = (const float*)d_in[4];  // (64,64)
    const float* b   = (const float*)d_in[5];  // (64,)
    float*       out = (float*)d_out;          // (N,T,64)

    char* ws = (char*)d_ws;
    size_t off = 0;
    auto alloc = [&](size_t bytes) {
        void* p = ws + off;
        off += (bytes + 255) & ~(size_t)255;
        return p;
    };
    unsigned short* yb  = (unsigned short*)alloc((size_t)ROWS * 64 * 2); // 10.24 MB
    int*            cnt = (int*) alloc((N_NODES + 1) * sizeof(int));     // +ovf_cnt
    int4*           ovf = (int4*)alloc((size_t)OVF_CAP * sizeof(int4));
    int*            ovf_cnt = cnt + N_NODES;

    // Bucket capacity: cap=64 (Poisson(32); P(deg>64) ~ 1e-7/node; tail goes
    // through the fused overflow path). Region = 10.24 MB of 8B records.
    size_t rem = (ws_size > off) ? (ws_size - off) : 0;
    int cap = (int)(rem / ((size_t)N_NODES * sizeof(uint2)));
    if (cap > 64) cap = 64;
    if (cap < 1) cap = 1;
    uint2* buckets = (uint2*)(ws + off);

    hipMemsetAsync(cnt, 0, (N_NODES + 1) * sizeof(int), stream);
    fused_build_kernel<<<SCATTER_BLOCKS + TRANSFORM_BLOCKS, 256, 0, stream>>>(
        x, W, yb, src, dst, ew, cnt, buckets, cap, ovf, ovf_cnt);
    accumulate_kernel<<<N_NODES / 4, 256, 0, stream>>>(
        yb, cnt, buckets, cap, ovf, ovf_cnt, b, out);
}